// Round 7
// baseline (550.945 us; speedup 1.0000x reference)
//
#include <hip/hip_runtime.h>
#include <math.h>

// Problem constants (from reference)
#define N_ROWS    16384
#define NC        1000
#define KVAL      5.0f
#define ALPHA     0.025f
#define N_ITER    80
#define MAX_SOLVE 12        // Newton passes; warm-started, early-exits in 1-3
#define EPS_P     1e-6f
#define EPJ       16        // elements per lane: 16*64 = 1024 >= 1000
#define ALN2      0.0173286795139986f   // ALPHA * ln(2)

// One wave (64 lanes) per row; lane holds elements e = j*64 + lane.
// Rows lock into a bitwise period-2 flush cycle at varying iterations, so
// static row->wave mapping is imbalance-bound (R6: VALUBusy 42%). This round:
// persistent waves steal rows from a global counter; each wave accumulates
// its own loss and exits independently (no LDS, no __syncthreads).
//
// Solver invariants (see R4/R5): v in [0.11,0.92] => upper clip never binds,
// nu* > 0, s(nu)=sum relu(v-nu) convex piecewise-linear => warm-started
// Newton converges globally & monotonically after one step.

template <int CTRL>
__device__ __forceinline__ float dpp_add(float x) {
    int t = __builtin_amdgcn_update_dpp(0, __float_as_int(x), CTRL, 0xf, 0xf, true);
    return x + __int_as_float(t);
}

// Full 64-lane sum -> uniform via readlane(63).
__device__ __forceinline__ float wave_sum(float x) {
    x = dpp_add<0x111>(x);  // row_shr:1
    x = dpp_add<0x112>(x);  // row_shr:2
    x = dpp_add<0x114>(x);  // row_shr:4
    x = dpp_add<0x118>(x);  // row_shr:8
    x = dpp_add<0x142>(x);  // row_bcast:15
    x = dpp_add<0x143>(x);  // row_bcast:31 -> lane63 = total
    return __int_as_float(__builtin_amdgcn_readlane(__float_as_int(x), 63));
}

__global__ __launch_bounds__(256, 8) void pgd_kernel(
        const float* __restrict__ x,
        const int*   __restrict__ y,
        double*       __restrict__ acc,
        unsigned int* __restrict__ counter) {
    const int lane = threadIdx.x & 63;
    const bool valid15 = lane < (NC - 15 * 64);  // lane < 40 for j==15

    double local_loss = 0.0;   // same value on all lanes; lane0 commits

    for (;;) {
        // ---- steal a row ----
        unsigned int r;
        if (lane == 0) r = atomicAdd(counter, 1u);
        r = (unsigned int)__shfl((int)r, 0, 64);
        if (r >= N_ROWS) break;

        const float* __restrict__ xr = x + (size_t)r * NC;

        float cc[EPJ];  // ALPHA * normalized logits
        float p[EPJ];
        float v[EPJ];
        float pp[EPJ];  // p two iterations back (odd-completion snapshots)

        // ---- load row + sum of squares (L2 normalize) ----
        float ss = 0.f;
#pragma unroll
        for (int j = 0; j < EPJ; ++j) {
            const int e = j * 64 + lane;
            float xv = (e < NC) ? xr[e] : 0.f;
            cc[j] = xv;
            ss += xv * xv;
        }
        ss = wave_sum(ss);
        const float sc = ALPHA / fmaxf(sqrtf(ss), 1e-12f);
#pragma unroll
        for (int j = 0; j < EPJ; ++j) cc[j] *= sc;

#pragma unroll
        for (int j = 0; j < EPJ; ++j) {
            p[j]  = KVAL / (float)NC;   // 0.005
            pp[j] = -1.f;               // impossible: first compare fails
        }
        if (!valid15) pp[15] = 0.f;     // pad lanes: p[15] always 0 -> compare true

        float nu_m1 = 0.f, nu_m2 = 0.f;

        for (int it = 0; it < N_ITER; ++it) {
            // ---- ascent: v = (p + alpha*c) + alpha*ln2*(log2(1-pc)-log2(pc)) ----
#pragma unroll
            for (int j = 0; j < EPJ; ++j) {
                float pc = fmaxf(p[j], EPS_P);
                float d  = __log2f(1.f - pc) - __log2f(pc);
                float vj = fmaf(ALN2, d, p[j] + cc[j]);
                if (j == 15) vj = valid15 ? vj : 0.f;  // pads: relu(0-nu)=0, nu>0
                v[j] = vj;
            }

            // ---- projection: warm-started Newton on convex s(nu)=K ----
            float nu = nu_m2;
            for (int pass = 0; pass < MAX_SOLVE; ++pass) {
                float s = 0.f;
                int   m = 0;
#pragma unroll
                for (int j = 0; j < EPJ; ++j) {
                    float t  = v[j] - nu;
                    float tc = fmaxf(t, 0.f);
                    p[j] = tc;                                          // fused update
                    s += tc;
                    m += (int)__builtin_popcountll(__ballot(t > 0.f));  // slope
                }
                s = wave_sum(s);
                if (m == 0) { nu = 0.f; continue; }   // restart below root (s(0)>K)
                float step = (s - KVAL) / (float)m;
                nu += step;
                if (fabsf(step) < 3e-8f) break;       // ~1 ULP: converged
            }
            nu_m2 = nu_m1;
            nu_m1 = nu;

            // ---- period-2 detection at odd it (completed count even, like 80) ----
            if (it & 1) {
                unsigned long long eq = ~0ull;
#pragma unroll
                for (int j = 0; j < EPJ; ++j) {
                    eq &= __ballot(p[j] == pp[j]);
                    pp[j] = p[j];
                }
                if (eq == ~0ull) break;   // bitwise period-2: P_final == P_current
            }
        }

        // ---- pick p[y], loss = -log(p_y + 1e-8) ----
        const int yv = y[r];            // wave-uniform
        const int jy = yv >> 6;
        const int ly = yv & 63;
        float sel = 0.f;
#pragma unroll
        for (int j = 0; j < EPJ; ++j) sel = (j == jy) ? p[j] : sel;
        const float py = __shfl(sel, ly, 64);
        local_loss += (double)(-logf(py + 1e-8f));
    }

    if (lane == 0 && local_loss != 0.0) atomicAdd(acc, local_loss);
}

__global__ void finalize_kernel(const double* __restrict__ acc,
                                float* __restrict__ out) {
    out[0] = (float)(acc[0] / (double)N_ROWS);
}

extern "C" void kernel_launch(void* const* d_in, const int* in_sizes, int n_in,
                              void* d_out, int out_size, void* d_ws, size_t ws_size,
                              hipStream_t stream) {
    const float* x = (const float*)d_in[0];
    const int*   y = (const int*)d_in[1];
    double*       acc     = (double*)d_ws;
    unsigned int* counter = (unsigned int*)((char*)d_ws + 8);

    (void)hipMemsetAsync(d_ws, 0, 16, stream);   // acc + counter (ws poisoned 0xAA)
    // exactly-resident persistent grid: 256 CU x 8 blocks x 4 waves = 8192 waves;
    // correctness does not depend on co-residency (late blocks find counter done).
    pgd_kernel<<<2048, 256, 0, stream>>>(x, y, acc, counter);
    finalize_kernel<<<1, 1, 0, stream>>>(acc, (float*)d_out);
}

// Round 8
// 371.701 us; speedup vs baseline: 1.4822x; 1.4822x over previous
//
#include <hip/hip_runtime.h>
#include <math.h>

// Problem constants (from reference)
#define N_ROWS    16384
#define NC        1000
#define KVAL      5.0f
#define ALPHA     0.025f
#define N_ITER    80
#define MAX_SOLVE 12        // Newton passes; warm-started, early-exits in 1-3
#define EPS_P     1e-6f
#define EPJ       16        // elements per lane: 16*64 = 1024 >= 1000
#define ALN2      0.0173286795139986f   // ALPHA * ln(2)

// One wave (64 lanes) per row; lane holds elements e = j*64 + lane.
// Persistent waves steal rows from a global counter (rows lock into the
// period-2 cycle at varying iterations -> static mapping is imbalance-bound,
// R6: VALUBusy 42%). REGISTER BUDGET: live state is ~80 regs/lane
// (cc/p/v/pp = 64 + temps); __launch_bounds__(256,4) gives 128/lane.
// (256,8) caps at 64/lane -> scratch spills (R7: WRITE_SIZE 73 MB, 15% VALU).
//
// Solver invariants (R4/R5): v in [0.11,0.92] => upper clip never binds,
// nu* > 0, s(nu)=sum relu(v-nu) convex piecewise-linear => warm-started
// Newton converges globally & monotonically after one step.

template <int CTRL>
__device__ __forceinline__ float dpp_add(float x) {
    int t = __builtin_amdgcn_update_dpp(0, __float_as_int(x), CTRL, 0xf, 0xf, true);
    return x + __int_as_float(t);
}

// Full 64-lane sum -> uniform via readlane(63).
__device__ __forceinline__ float wave_sum(float x) {
    x = dpp_add<0x111>(x);  // row_shr:1
    x = dpp_add<0x112>(x);  // row_shr:2
    x = dpp_add<0x114>(x);  // row_shr:4
    x = dpp_add<0x118>(x);  // row_shr:8
    x = dpp_add<0x142>(x);  // row_bcast:15
    x = dpp_add<0x143>(x);  // row_bcast:31 -> lane63 = total
    return __int_as_float(__builtin_amdgcn_readlane(__float_as_int(x), 63));
}

__global__ __launch_bounds__(256, 4) void pgd_kernel(
        const float* __restrict__ x,
        const int*   __restrict__ y,
        double*       __restrict__ acc,
        unsigned int* __restrict__ counter) {
    const int lane = threadIdx.x & 63;
    const bool valid15 = lane < (NC - 15 * 64);  // lane < 40 for j==15

    double local_loss = 0.0;   // same value on all lanes; lane0 commits

    for (;;) {
        // ---- steal a row ----
        unsigned int r;
        if (lane == 0) r = atomicAdd(counter, 1u);
        r = (unsigned int)__shfl((int)r, 0, 64);
        if (r >= N_ROWS) break;

        const float* __restrict__ xr = x + (size_t)r * NC;

        float cc[EPJ];  // ALPHA * normalized logits
        float p[EPJ];
        float v[EPJ];
        float pp[EPJ];  // p two iterations back (odd-completion snapshots)

        // ---- load row + sum of squares (L2 normalize) ----
        float ss = 0.f;
#pragma unroll
        for (int j = 0; j < EPJ; ++j) {
            const int e = j * 64 + lane;
            float xv = (e < NC) ? xr[e] : 0.f;
            cc[j] = xv;
            ss += xv * xv;
        }
        ss = wave_sum(ss);
        const float sc = ALPHA / fmaxf(sqrtf(ss), 1e-12f);
#pragma unroll
        for (int j = 0; j < EPJ; ++j) cc[j] *= sc;

#pragma unroll
        for (int j = 0; j < EPJ; ++j) {
            p[j]  = KVAL / (float)NC;   // 0.005
            pp[j] = -1.f;               // impossible: first compare fails
        }
        if (!valid15) pp[15] = 0.f;     // pad lanes: p[15] always 0 -> compare true

        float nu_m1 = 0.f, nu_m2 = 0.f;

        for (int it = 0; it < N_ITER; ++it) {
            // ---- ascent: v = (p + alpha*c) + alpha*ln2*(log2(1-pc)-log2(pc)) ----
#pragma unroll
            for (int j = 0; j < EPJ; ++j) {
                float pc = fmaxf(p[j], EPS_P);
                float d  = __log2f(1.f - pc) - __log2f(pc);
                float vj = fmaf(ALN2, d, p[j] + cc[j]);
                if (j == 15) vj = valid15 ? vj : 0.f;  // pads: relu(0-nu)=0, nu>0
                v[j] = vj;
            }

            // ---- projection: warm-started Newton on convex s(nu)=K ----
            float nu = nu_m2;
            for (int pass = 0; pass < MAX_SOLVE; ++pass) {
                float s = 0.f;
                int   m = 0;
#pragma unroll
                for (int j = 0; j < EPJ; ++j) {
                    float t  = v[j] - nu;
                    float tc = fmaxf(t, 0.f);
                    p[j] = tc;                                          // fused update
                    s += tc;
                    m += (int)__builtin_popcountll(__ballot(t > 0.f));  // slope
                }
                s = wave_sum(s);
                if (m == 0) { nu = 0.f; continue; }   // restart below root (s(0)>K)
                float step = (s - KVAL) / (float)m;
                nu += step;
                if (fabsf(step) < 3e-8f) break;       // ~1 ULP: converged
            }
            nu_m2 = nu_m1;
            nu_m1 = nu;

            // ---- period-2 detection at odd it (completed count even, like 80) ----
            if (it & 1) {
                unsigned long long eq = ~0ull;
#pragma unroll
                for (int j = 0; j < EPJ; ++j) {
                    eq &= __ballot(p[j] == pp[j]);
                    pp[j] = p[j];
                }
                if (eq == ~0ull) break;   // bitwise period-2: P_final == P_current
            }
        }

        // ---- pick p[y], loss = -log(p_y + 1e-8) ----
        const int yv = y[r];            // wave-uniform
        const int jy = yv >> 6;
        const int ly = yv & 63;
        float sel = 0.f;
#pragma unroll
        for (int j = 0; j < EPJ; ++j) sel = (j == jy) ? p[j] : sel;
        const float py = __shfl(sel, ly, 64);
        local_loss += (double)(-logf(py + 1e-8f));
    }

    if (lane == 0 && local_loss != 0.0) atomicAdd(acc, local_loss);
}

__global__ void finalize_kernel(const double* __restrict__ acc,
                                float* __restrict__ out) {
    out[0] = (float)(acc[0] / (double)N_ROWS);
}

extern "C" void kernel_launch(void* const* d_in, const int* in_sizes, int n_in,
                              void* d_out, int out_size, void* d_ws, size_t ws_size,
                              hipStream_t stream) {
    const float* x = (const float*)d_in[0];
    const int*   y = (const int*)d_in[1];
    double*       acc     = (double*)d_ws;
    unsigned int* counter = (unsigned int*)((char*)d_ws + 8);

    (void)hipMemsetAsync(d_ws, 0, 16, stream);   // acc + counter (ws poisoned 0xAA)
    // persistent grid at the (256,4) occupancy: 256 CU x 4 blocks x 4 waves
    // = 4096 waves; correctness does not depend on co-residency.
    pgd_kernel<<<1024, 256, 0, stream>>>(x, y, acc, counter);
    finalize_kernel<<<1, 1, 0, stream>>>(acc, (float*)d_out);
}

// Round 9
// 222.065 us; speedup vs baseline: 2.4810x; 1.6738x over previous
//
#include <hip/hip_runtime.h>
#include <math.h>

// Problem constants (from reference)
#define N_ROWS    16384
#define NC        1000
#define KVAL      5.0f
#define ALPHA     0.025f
#define N_ITER    80
#define MAX_SOLVE 12        // Newton passes; warm-started, early-exits in 1-3
#define EPS_P     1e-6f
#define EPJ       16        // elements per lane: 16*64 = 1024 >= 1000
#define ALN2      0.0173286795139986f   // ALPHA * ln(2)
#define N_ACC     256       // distributed loss accumulators (kills atomic serialize)

// One 64-thread block (= one wave) per row; lane holds elements e = j*64+lane.
// R8 lesson: persistent work-stealing starves the SIMDs (4 resident waves,
// nothing to backfill during steal+load stalls -> VALUBusy 25%). Streaming
// 1-wave blocks make the HW dispatcher the work-stealer at wave granularity:
// retired rows are backfilled by fresh blocks whose loads overlap other
// waves' compute. R7 lesson: live state ~80 regs/lane -> need 128/lane cap,
// i.e. min-waves-per-EU = 4. (8 -> 64/lane -> 73 MB scratch spills.)
//
// Solver invariants (R4/R5): v in [0.11,0.92] => upper clip never binds,
// nu* > 0, s(nu)=sum relu(v-nu) convex piecewise-linear => warm-started
// Newton converges globally & monotonically after one step.
// Dynamics (R6): superstable bitwise period-2 flush cycle => early exit,
// checked at odd it so the completed count is even (parity of N_ITER=80).

template <int CTRL>
__device__ __forceinline__ float dpp_add(float x) {
    int t = __builtin_amdgcn_update_dpp(0, __float_as_int(x), CTRL, 0xf, 0xf, true);
    return x + __int_as_float(t);
}

// Full 64-lane sum -> uniform via readlane(63).
__device__ __forceinline__ float wave_sum(float x) {
    x = dpp_add<0x111>(x);  // row_shr:1
    x = dpp_add<0x112>(x);  // row_shr:2
    x = dpp_add<0x114>(x);  // row_shr:4
    x = dpp_add<0x118>(x);  // row_shr:8
    x = dpp_add<0x142>(x);  // row_bcast:15
    x = dpp_add<0x143>(x);  // row_bcast:31 -> lane63 = total
    return __int_as_float(__builtin_amdgcn_readlane(__float_as_int(x), 63));
}

__global__ __launch_bounds__(64, 4) void pgd_kernel(
        const float* __restrict__ x,
        const int*   __restrict__ y,
        double*      __restrict__ acc) {
    const int lane = threadIdx.x;
    const int row  = blockIdx.x;
    const bool valid15 = lane < (NC - 15 * 64);  // lane < 40 for j==15

    const float* __restrict__ xr = x + (size_t)row * NC;
    const int yv = y[row];          // prefetch: independent, schedules early

    float cc[EPJ];  // ALPHA * normalized logits
    float p[EPJ];
    float v[EPJ];
    float pp[EPJ];  // p two iterations back (odd-completion snapshots)

    // ---- load row + sum of squares (L2 normalize) ----
    float ss = 0.f;
#pragma unroll
    for (int j = 0; j < EPJ; ++j) {
        const int e = j * 64 + lane;
        float xv = (e < NC) ? xr[e] : 0.f;
        cc[j] = xv;
        ss += xv * xv;
    }
    ss = wave_sum(ss);
    const float sc = ALPHA / fmaxf(sqrtf(ss), 1e-12f);
#pragma unroll
    for (int j = 0; j < EPJ; ++j) cc[j] *= sc;

#pragma unroll
    for (int j = 0; j < EPJ; ++j) {
        p[j]  = KVAL / (float)NC;   // 0.005
        pp[j] = -1.f;               // impossible: first compare fails
    }
    if (!valid15) pp[15] = 0.f;     // pad lanes: p[15] always 0 -> compare true

    float nu_m1 = 0.f, nu_m2 = 0.f;

    for (int it = 0; it < N_ITER; ++it) {
        // ---- ascent: v = (p + alpha*c) + alpha*ln2*(log2(1-pc)-log2(pc)) ----
#pragma unroll
        for (int j = 0; j < EPJ; ++j) {
            float pc = fmaxf(p[j], EPS_P);
            float d  = __log2f(1.f - pc) - __log2f(pc);
            float vj = fmaf(ALN2, d, p[j] + cc[j]);
            if (j == 15) vj = valid15 ? vj : 0.f;  // pads: relu(0-nu)=0, nu>0
            v[j] = vj;
        }

        // ---- projection: warm-started Newton on convex s(nu)=K ----
        float nu = nu_m2;
        for (int pass = 0; pass < MAX_SOLVE; ++pass) {
            float s = 0.f;
            int   m = 0;
#pragma unroll
            for (int j = 0; j < EPJ; ++j) {
                float t  = v[j] - nu;
                float tc = fmaxf(t, 0.f);
                p[j] = tc;                                          // fused update
                s += tc;
                m += (int)__builtin_popcountll(__ballot(t > 0.f));  // slope
            }
            s = wave_sum(s);
            if (m == 0) { nu = 0.f; continue; }   // restart below root (s(0)>K)
            float step = (s - KVAL) / (float)m;
            nu += step;
            if (fabsf(step) < 3e-8f) break;       // ~1 ULP: converged
        }
        nu_m2 = nu_m1;
        nu_m1 = nu;

        // ---- period-2 detection at odd it (completed count even, like 80) ----
        if (it & 1) {
            unsigned long long eq = ~0ull;
#pragma unroll
            for (int j = 0; j < EPJ; ++j) {
                eq &= __ballot(p[j] == pp[j]);
                pp[j] = p[j];
            }
            if (eq == ~0ull) break;   // bitwise period-2: P_final == P_current
        }
    }

    // ---- pick p[y], loss = -log(p_y + 1e-8) ----
    const int jy = yv >> 6;
    const int ly = yv & 63;
    float sel = 0.f;
#pragma unroll
    for (int j = 0; j < EPJ; ++j) sel = (j == jy) ? p[j] : sel;
    const float py = __shfl(sel, ly, 64);

    if (lane == 0)
        atomicAdd(&acc[row & (N_ACC - 1)], (double)(-logf(py + 1e-8f)));
}

__global__ void finalize_kernel(const double* __restrict__ acc,
                                float* __restrict__ out) {
    const int l = threadIdx.x;      // 64 lanes
    double s = acc[l] + acc[l + 64] + acc[l + 128] + acc[l + 192];
#pragma unroll
    for (int m = 32; m >= 1; m >>= 1) s += __shfl_down(s, m, 64);
    if (l == 0) out[0] = (float)(s / (double)N_ROWS);
}

extern "C" void kernel_launch(void* const* d_in, const int* in_sizes, int n_in,
                              void* d_out, int out_size, void* d_ws, size_t ws_size,
                              hipStream_t stream) {
    const float* x = (const float*)d_in[0];
    const int*   y = (const int*)d_in[1];
    double* acc = (double*)d_ws;

    (void)hipMemsetAsync(acc, 0, N_ACC * sizeof(double), stream);  // ws poisoned 0xAA
    // streaming 1-wave blocks: HW dispatcher backfills at wave granularity
    pgd_kernel<<<N_ROWS, 64, 0, stream>>>(x, y, acc);
    finalize_kernel<<<1, 64, 0, stream>>>(acc, (float*)d_out);
}

// Round 10
// 173.815 us; speedup vs baseline: 3.1697x; 1.2776x over previous
//
#include <hip/hip_runtime.h>
#include <math.h>

// Problem constants (from reference)
#define N_ROWS    16384
#define NC        1000
#define KVAL      5.0f
#define ALPHA     0.025f
#define N_ITER    80
#define MAX_SOLVE 12        // Newton passes; warm-started, early-exits in 1-3
#define EPS_P     1e-6f
#define EPJ       16        // elements per lane: 16*64 = 1024 >= 1000
#define ALN2      0.0173286795139986f   // ALPHA * ln(2)
#define N_ACC     256       // distributed loss accumulators

// One 64-thread block (= one wave) per row; lane holds elements e = j*64+lane.
// R9 lesson: 4 arrays x 16 floats of live state -> ~2 waves/SIMD resident
// (Occupancy 23%) -> VALU idles on dependency chains. This round state is
// cc[16] + v[16] + scalar nu ONLY:
//   p == relu(v - nu) by construction -> recompute instead of store (p[] gone)
//   period-2 detected by a two-back FINGERPRINT (bitwise nu, interior count m,
//   checksums sum(v*cc), sum(v*(e+1))) instead of element-exact pp[] compare.
// (v,nu) determines p, so true period-2 => fingerprint period-2; a false
// positive needs two independent fp32 checksums to collide below 1 ulp.
// R7 lesson kept in mind: cap regs via __launch_bounds__(64,6) (~80/lane,
// est. alloc ~50 -> no spill, up to 8 waves/SIMD).
//
// Solver invariants (R4/R5): v in [0.11,0.92] => upper clip never binds,
// nu* > 0, s(nu)=sum relu(v-nu) convex piecewise-linear => warm-started
// Newton converges globally & monotonically after one step.

template <int CTRL>
__device__ __forceinline__ float dpp_add(float x) {
    int t = __builtin_amdgcn_update_dpp(0, __float_as_int(x), CTRL, 0xf, 0xf, true);
    return x + __int_as_float(t);
}

// Full 64-lane sum -> uniform via readlane(63).
__device__ __forceinline__ float wave_sum(float x) {
    x = dpp_add<0x111>(x);  // row_shr:1
    x = dpp_add<0x112>(x);  // row_shr:2
    x = dpp_add<0x114>(x);  // row_shr:4
    x = dpp_add<0x118>(x);  // row_shr:8
    x = dpp_add<0x142>(x);  // row_bcast:15
    x = dpp_add<0x143>(x);  // row_bcast:31 -> lane63 = total
    return __int_as_float(__builtin_amdgcn_readlane(__float_as_int(x), 63));
}

__global__ __launch_bounds__(64, 6) void pgd_kernel(
        const float* __restrict__ x,
        const int*   __restrict__ y,
        double*      __restrict__ acc) {
    const int lane = threadIdx.x;
    const int row  = blockIdx.x;
    const bool valid15 = lane < (NC - 15 * 64);  // lane < 40 for j==15

    const float* __restrict__ xr = x + (size_t)row * NC;
    const int yv = y[row];            // prefetch: independent, schedules early
    const float flane = (float)(lane + 1);   // checksum weight base

    float cc[EPJ];  // ALPHA * normalized logits
    float v[EPJ];   // pre-projection iterate; p == relu(v - nu)

    // ---- load row + sum of squares (L2 normalize) ----
    float ss = 0.f;
#pragma unroll
    for (int j = 0; j < EPJ; ++j) {
        const int e = j * 64 + lane;
        float xv = (e < NC) ? xr[e] : 0.f;
        cc[j] = xv;
        ss += xv * xv;
    }
    ss = wave_sum(ss);
    const float sc = ALPHA / fmaxf(sqrtf(ss), 1e-12f);
#pragma unroll
    for (int j = 0; j < EPJ; ++j) cc[j] *= sc;

    // init so relu(v - nu) == p0 = 0.005 exactly (pads: 0)
#pragma unroll
    for (int j = 0; j < EPJ; ++j) v[j] = KVAL / (float)NC;
    if (!valid15) v[15] = 0.f;
    float nu = 0.f;                  // nu_{t-1} (projection shift for current v)
    float nu_m1 = 0.f, nu_m2 = 0.f;  // warm-start history

    // fingerprint history (two-back): {nu, m, chk1, chk2}
    float fA_nu = -1.f, fA_c1 = 0.f, fA_c2 = 0.f;  int fA_m = -1;
    float fB_nu = -2.f, fB_c1 = 0.f, fB_c2 = 0.f;  int fB_m = -2;

    for (int it = 0; it < N_ITER; ++it) {
        // ---- ascent: p = relu(v - nu); v' = p + alpha*c + aln2*(log2(1-pc)-log2(pc)) ----
#pragma unroll
        for (int j = 0; j < EPJ; ++j) {
            float pj = fmaxf(v[j] - nu, 0.f);
            float pc = fmaxf(pj, EPS_P);
            float d  = __log2f(1.f - pc) - __log2f(pc);
            float vj = fmaf(ALN2, d, pj + cc[j]);
            if (j == 15) vj = valid15 ? vj : 0.f;   // pads stay 0 (nu >= 0)
            v[j] = vj;
        }

        // ---- projection: warm-started Newton on convex s(nu)=K ----
        float nu_new = nu_m2;
        int   m_fin  = 0;
        for (int pass = 0; pass < MAX_SOLVE; ++pass) {
            float s = 0.f;
            int   m = 0;
#pragma unroll
            for (int j = 0; j < EPJ; ++j) {
                float t = v[j] - nu_new;
                s += fmaxf(t, 0.f);
                m += (int)__builtin_popcountll(__ballot(t > 0.f));  // slope
            }
            s = wave_sum(s);
            if (m == 0) { nu_new = 0.f; continue; }  // restart below root (s(0)>K)
            m_fin = m;
            float step = (s - KVAL) / (float)m;
            nu_new += step;
            if (fabsf(step) < 3e-8f) break;          // ~1 ULP: converged
        }
        nu_m2 = nu_m1;
        nu_m1 = nu_new;
        nu    = nu_new;   // p_t == relu(v - nu)

        // ---- period-2 fingerprint at odd it (completed count even, like 80) ----
        if (it & 1) {
            float c1 = 0.f, c2 = 0.f;
#pragma unroll
            for (int j = 0; j < EPJ; ++j) {
                c1 = fmaf(v[j], cc[j], c1);
                c2 = fmaf(v[j], flane + (float)(j * 64), c2);
            }
            c1 = wave_sum(c1);
            c2 = wave_sum(c2);
            const bool hit = (__float_as_int(nu) == __float_as_int(fB_nu)) &&
                             (m_fin == fB_m) &&
                             (__float_as_int(c1) == __float_as_int(fB_c1)) &&
                             (__float_as_int(c2) == __float_as_int(fB_c2));
            fB_nu = fA_nu; fB_m = fA_m; fB_c1 = fA_c1; fB_c2 = fA_c2;
            fA_nu = nu;    fA_m = m_fin; fA_c1 = c1;   fA_c2 = c2;
            if (hit) break;   // bitwise period-2: (v,nu) == two iterations back
        }
    }

    // ---- pick p[y] = relu(v[y]-nu), loss = -log(p_y + 1e-8) ----
    const int jy = yv >> 6;
    const int ly = yv & 63;
    float sel = 0.f;
#pragma unroll
    for (int j = 0; j < EPJ; ++j) sel = (j == jy) ? v[j] : sel;
    const float vy = __shfl(sel, ly, 64);
    const float py = fminf(fmaxf(vy - nu, 0.f), 1.f);

    if (lane == 0)
        atomicAdd(&acc[row & (N_ACC - 1)], (double)(-logf(py + 1e-8f)));
}

__global__ void finalize_kernel(const double* __restrict__ acc,
                                float* __restrict__ out) {
    const int l = threadIdx.x;      // 64 lanes
    double s = acc[l] + acc[l + 64] + acc[l + 128] + acc[l + 192];
#pragma unroll
    for (int m = 32; m >= 1; m >>= 1) s += __shfl_down(s, m, 64);
    if (l == 0) out[0] = (float)(s / (double)N_ROWS);
}

extern "C" void kernel_launch(void* const* d_in, const int* in_sizes, int n_in,
                              void* d_out, int out_size, void* d_ws, size_t ws_size,
                              hipStream_t stream) {
    const float* x = (const float*)d_in[0];
    const int*   y = (const int*)d_in[1];
    double* acc = (double*)d_ws;

    (void)hipMemsetAsync(acc, 0, N_ACC * sizeof(double), stream);  // ws poisoned 0xAA
    pgd_kernel<<<N_ROWS, 64, 0, stream>>>(x, y, acc);
    finalize_kernel<<<1, 64, 0, stream>>>(acc, (float*)d_out);
}